// Round 8
// baseline (48.635 us; speedup 1.0000x reference)
//
#include <hip/hip_runtime.h>

#define WPB 4              // rows (waves) per block
#define TPB (WPB * 64)
#define NT_ 2048
#define EPC 8              // elems per lane per chunk
#define NCH 4              // chunks: 64 lanes * 8 * 4 = 2048
#define BW 16              // band half-width of T^-1 (float band)
#define BD (2*BW+1)        // 33
#define BAND_BYTES (BD*256*4)
#define H_P 0.00390625f    // p spacing = 1/256, exact
#define RTPB 1024

__device__ __forceinline__ double shfl_down_f64(double x, int off) {
  union { double d; int i[2]; } u; u.d = x;
  u.i[0] = __shfl_down(u.i[0], off, 64);
  u.i[1] = __shfl_down(u.i[1], off, 64);
  return u.d;
}

// ---------------- setup: banded inverse of T = (1/256)*tridiag(1,4,1), 255x255 --------
__global__ void w2_setup(float* __restrict__ bandS) {
  __shared__ double sh_L[256];
  __shared__ double sh_winv[256];
  const int tid = threadIdx.x;
  if (tid < 255) {
    double d, dm;
    if (tid >= 20) {
      d = dm = 3.7320508075688772935;          // 2+sqrt(3), fully converged
    } else {
      d = 4.0; dm = 0.0;
      for (int i = 1; i <= tid; i++) { dm = d; d = 4.0 - 1.0 / d; }
    }
    sh_winv[tid] = 256.0 / d;
    sh_L[tid] = (tid == 0) ? 0.0 : 1.0 / dm;
  }
  __syncthreads();
  const int j = tid;
  const double H = (double)H_P;
  if (j < 255) {
    double y[BW + 1];
    y[0] = 1.0;
    #pragma unroll
    for (int m = 1; m <= BW; m++) {
      int i = j + m;
      y[m] = (i <= 254) ? (-sh_L[i] * y[m - 1]) : 0.0;
    }
    double xn = 0.0;
    #pragma unroll
    for (int m = BW; m >= 0; m--) {
      int i = j + m;
      double val = 0.0;
      if (i <= 254) {
        double num = y[m] - ((i < 254) ? H * xn : 0.0);
        val = num * sh_winv[i];
        xn = val;
      }
      bandS[(m + BW) * 256 + j] = (float)val;
    }
    #pragma unroll
    for (int m = -1; m >= -BW; m--) {
      int i = j + m;
      double val = 0.0;
      if (i >= 0) {
        val = (-H * xn) * sh_winv[i];
        xn = val;
      }
      bandS[(m + BW) * 256 + j] = (float)val;
    }
  } else {
    for (int mm = 0; mm < BD; mm++) bandS[mm * 256 + j] = 0.0f;
  }
}

// ---------------- main: ONE WAVE PER ROW, zero __syncthreads ----------------
// NOTE (round 3): no min-waves arg in __launch_bounds__ (VGPR squeeze -> HBM spill).
// NOTE (round 5): no same-address atomic fusion of the final reduce.
// Cross-lane LDS handoffs are intra-wave: DS ops are in program order per wave;
// wave_barrier() fences the compiler. LDS slices are per-wave (wid-indexed).
__global__ __launch_bounds__(TPB) void w2_main(
    const float* __restrict__ f, const float* __restrict__ obs,
    const float* __restrict__ t, const float* __restrict__ bandS,
    double* __restrict__ row_out) {
  __shared__ float  s_q[WPB][260];
  __shared__ float  s_rm[WPB][288];    // rhs during MV, then M[0..256]
  __shared__ float4 s_coef[WPB][256];

  const int tid = threadIdx.x;
  const int lane = tid & 63;
  const int wid = tid >> 6;
  const int row = (int)blockIdx.x * WPB + wid;

  float*  q    = s_q[wid];
  float*  rm   = s_rm[wid];
  float4* coef = s_coef[wid];

  const float* orow = obs + (size_t)row * NT_;
  const float* frow = f + (size_t)row * NT_;
  const double dx = (double)t[1] - (double)t[0];

  // ======== pass 0 (fused): row totals for obs^2 and f^2 pair-sums ========
  float totA = 0.0f, totB = 0.0f;
  for (int c = 0; c < NCH; c++) {
    const int idx = c * 512 + lane * EPC;
    const int km = (NT_ - 1 - idx < EPC) ? (NT_ - 1 - idx) : EPC;
    float4 a0 = *reinterpret_cast<const float4*>(orow + idx);
    float4 a1 = *reinterpret_cast<const float4*>(orow + idx + 4);
    float4 b0 = *reinterpret_cast<const float4*>(frow + idx);
    float4 b1 = *reinterpret_cast<const float4*>(frow + idx + 4);
    float oe[9] = {a0.x,a0.y,a0.z,a0.w,a1.x,a1.y,a1.z,a1.w,
                   (idx + 8 < NT_) ? orow[idx + 8] : 0.0f};
    float fe[9] = {b0.x,b0.y,b0.z,b0.w,b1.x,b1.y,b1.z,b1.w,
                   (idx + 8 < NT_) ? frow[idx + 8] : 0.0f};
    #pragma unroll
    for (int k = 0; k < EPC; k++) {
      if (k < km) {
        totA += oe[k]*oe[k] + oe[k+1]*oe[k+1];
        totB += fe[k]*fe[k] + fe[k+1]*fe[k+1];
      }
    }
  }
  #pragma unroll
  for (int off = 1; off < 64; off <<= 1) {
    totA += __shfl_xor(totA, off, 64);
    totB += __shfl_xor(totB, off, 64);
  }
  const float invA = 1.0f / totA;
  const float invB = 1.0f / totB;

  // ======== Phase A pass 2: chunked scan + quantile scatter ========
  float carry = 0.0f;
  for (int c = 0; c < NCH; c++) {
    const int idx = c * 512 + lane * EPC;
    const int km = (NT_ - 1 - idx < EPC) ? (NT_ - 1 - idx) : EPC;
    float4 a0 = *reinterpret_cast<const float4*>(orow + idx);
    float4 a1 = *reinterpret_cast<const float4*>(orow + idx + 4);
    float oe[9] = {a0.x,a0.y,a0.z,a0.w,a1.x,a1.y,a1.z,a1.w,
                   (idx + 8 < NT_) ? orow[idx + 8] : 0.0f};
    float4 t0 = *reinterpret_cast<const float4*>(t + idx);
    float4 t1 = *reinterpret_cast<const float4*>(t + idx + 4);
    float tq[9] = {t0.x,t0.y,t0.z,t0.w,t1.x,t1.y,t1.z,t1.w,
                   (idx + 8 < NT_) ? t[idx + 8] : 0.0f};
    float sA[EPC];
    float ep = 0.0f;
    #pragma unroll
    for (int k = 0; k < EPC; k++) {
      sA[k] = oe[k]*oe[k] + oe[k+1]*oe[k+1];
      if (k < km) ep += sA[k];
    }
    // wave inclusive scan
    float v = ep;
    #pragma unroll
    for (int off = 1; off < 64; off <<= 1) {
      float w = __shfl_up(v, off, 64);
      if (lane >= off) v += w;
    }
    float excl = __shfl_up(v, 1, 64);
    if (lane == 0) excl = 0.0f;
    const float run = carry + excl;      // bit-consistent with left neighbor's incl
    const float incl = carry + v;        // bit-consistent with right neighbor's run
    // scatter: p[j]=j/256 exact; p[j] <= c  <=>  j <= floor(256*c)
    float cprev = fminf(run * invA, 1.0f);
    int j = (int)(cprev * 256.0f) + 1;
    float r = run;
    #pragma unroll
    for (int k = 0; k < EPC; k++) {
      if (k < km) {
        float cu_uns = (k == km - 1) ? incl : (r + sA[k]);
        r = cu_uns;
        float cu = fminf(cu_uns * invA, 1.0f);
        int jh = (int)(cu * 256.0f);
        float tqv = tq[k + 1];
        for (; j <= jh; j++) q[j] = tqv;
      }
    }
    if (c == 0 && lane == 0) q[0] = tq[0];           // p[0]=0 -> cdf idx 0
    if (c == NCH - 1 && lane == 63) {                // p[j] > cdf_max -> idx NT-1
      float tqv = tq[7];
      for (; j <= 256; j++) q[j] = tqv;
    }
    carry += __shfl(v, 63, 64);
  }
  __builtin_amdgcn_wave_barrier();

  // ======== spline rhs ========
  if (lane < BW) rm[lane] = 0.0f;
  if (lane >= 48) rm[271 + (lane - 48)] = 0.0f;      // 271..286
  #pragma unroll
  for (int s = 0; s < 4; s++) {
    int rr = lane + 64 * s;
    if (rr < 255) {
      float sl0 = (q[rr + 1] - q[rr]) * 256.0f;
      float sl1 = (q[rr + 2] - q[rr + 1]) * 256.0f;
      rm[BW + rr] = 6.0f * (sl1 - sl0);
    }
  }
  __builtin_amdgcn_wave_barrier();

  // ======== banded MV (reads all rhs BEFORE any M write; separate loops) ========
  float Macc[4];
  #pragma unroll
  for (int s = 0; s < 4; s++) {
    int rr = lane + 64 * s;
    float acc = 0.0f;
    if (rr < 255) {
      #pragma unroll 11
      for (int dd = 0; dd < BD; dd++)
        acc += bandS[dd * 256 + rr] * rm[rr + dd];
    }
    Macc[s] = acc;
  }
  __builtin_amdgcn_wave_barrier();
  #pragma unroll
  for (int s = 0; s < 4; s++) {
    int rr = lane + 64 * s;
    if (rr < 255) rm[rr + 1] = Macc[s];              // M[i] lives at rm[i]
  }
  if (lane == 0) { rm[0] = 0.0f; rm[256] = 0.0f; }
  __builtin_amdgcn_wave_barrier();

  // ======== coefficients ========
  #pragma unroll
  for (int s = 0; s < 4; s++) {
    int i = lane + 64 * s;
    float q0 = q[i], q1 = q[i + 1];
    float Mi = rm[i], Mi1 = rm[i + 1];
    float sl = (q1 - q0) * 256.0f;
    float b = sl - H_P * (2.0f * Mi + Mi1) * (1.0f / 6.0f);
    coef[i] = make_float4(q0, b, 0.5f * Mi, (Mi1 - Mi) * (256.0f / 6.0f));
  }
  __builtin_amdgcn_wave_barrier();

  // ======== Phase B: chunked scan + spline eval + weighted trapz ========
  float carry2 = 0.0f;
  double wsum = 0.0;
  float wv_first = 0.0f, wv_last = 0.0f;
  for (int c = 0; c < NCH; c++) {
    const int idx = c * 512 + lane * EPC;
    const int km = (NT_ - 1 - idx < EPC) ? (NT_ - 1 - idx) : EPC;
    float4 b0 = *reinterpret_cast<const float4*>(frow + idx);
    float4 b1 = *reinterpret_cast<const float4*>(frow + idx + 4);
    float fe[9] = {b0.x,b0.y,b0.z,b0.w,b1.x,b1.y,b1.z,b1.w,
                   (idx + 8 < NT_) ? frow[idx + 8] : 0.0f};
    float4 t0 = *reinterpret_cast<const float4*>(t + idx);
    float4 t1 = *reinterpret_cast<const float4*>(t + idx + 4);
    float tq[8] = {t0.x,t0.y,t0.z,t0.w,t1.x,t1.y,t1.z,t1.w};
    float sB[EPC];
    float ep2 = 0.0f;
    #pragma unroll
    for (int k = 0; k < EPC; k++) {
      sB[k] = fe[k]*fe[k] + fe[k+1]*fe[k+1];
      if (k < km) ep2 += sB[k];
    }
    float v = ep2;
    #pragma unroll
    for (int off = 1; off < 64; off <<= 1) {
      float w = __shfl_up(v, off, 64);
      if (lane >= off) v += w;
    }
    float excl = __shfl_up(v, 1, 64);
    if (lane == 0) excl = 0.0f;
    float r2 = carry2 + excl;
    float csum = 0.0f;
    #pragma unroll
    for (int k = 0; k < EPC; k++) {
      if (k > 0) r2 += sB[k - 1];
      float F = r2 * invB;
      float G = F * 256.0f;                          // exact scale
      int sg = (int)ceilf(G) - 1;                    // searchsorted(p,F,'left')-1
      if (sg < 0) sg = 0;
      if (sg > 255) sg = 255;
      float frac = F - (float)sg * H_P;
      float4 cf = coef[sg];
      float val = cf.x + frac * (cf.y + frac * (cf.z + frac * cf.w));
      float diff = tq[k] - val;
      float wv = diff * diff * fe[k];
      if (c == 0 && k == 0 && lane == 0) wv_first = wv;
      if (c == NCH - 1 && k == EPC - 1 && lane == 63) wv_last = wv;
      csum += wv;
    }
    wsum += (double)csum;
    carry2 += __shfl(v, 63, 64);
  }

  // wave f64 reduce + row write
  double rtot = wsum;
  #pragma unroll
  for (int off = 32; off >= 1; off >>= 1) rtot += shfl_down_f64(rtot, off);
  float wl = __shfl(wv_last, 63, 64);
  if (lane == 0) {
    row_out[row] = (rtot - 0.5 * ((double)wv_first + (double)wl)) * dx;
  }
}

__global__ __launch_bounds__(RTPB) void w2_reduce(const double* __restrict__ row_out,
                                                  int ntr, float* __restrict__ out) {
  __shared__ double s[RTPB / 64];
  int tid = threadIdx.x, lane = tid & 63, wid = tid >> 6;
  double v = 0.0;
  for (int i = tid; i < ntr; i += RTPB) v += row_out[i];
  #pragma unroll
  for (int off = 32; off >= 1; off >>= 1) v += shfl_down_f64(v, off);
  if (lane == 0) s[wid] = v;
  __syncthreads();
  if (tid == 0) {
    double tot = 0.0;
    #pragma unroll
    for (int i = 0; i < RTPB / 64; i++) tot += s[i];
    out[0] = (float)tot;
  }
}

extern "C" void kernel_launch(void* const* d_in, const int* in_sizes, int n_in,
                              void* d_out, int out_size, void* d_ws, size_t ws_size,
                              hipStream_t stream) {
  const float* f   = (const float*)d_in[0];
  const float* obs = (const float*)d_in[1];
  const float* t   = (const float*)d_in[2];
  int nt = in_sizes[2];          // 2048
  int ntr = in_sizes[0] / nt;    // 4096

  float* bandS = (float*)d_ws;
  double* rows = (double*)((char*)d_ws + BAND_BYTES);

  hipLaunchKernelGGL(w2_setup, dim3(1), dim3(256), 0, stream, bandS);
  hipLaunchKernelGGL(w2_main, dim3(ntr / WPB), dim3(TPB), 0, stream,
                     f, obs, t, bandS, rows);
  hipLaunchKernelGGL(w2_reduce, dim3(1), dim3(RTPB), 0, stream,
                     rows, ntr, (float*)d_out);
}

// Round 9
// 42.382 us; speedup vs baseline: 1.1475x; 1.1475x over previous
//
#include <hip/hip_runtime.h>

#define TPB 256
#define NT_ 2048
#define NQ_ 257
#define EPT 8              // NT_/TPB
#define BW 16              // band half-width of T^-1 (float band)
#define BD (2*BW+1)        // 33
#define BAND_BYTES (BD*256*4)
#define H_P 0.00390625f    // p spacing = 1/256, exact
#define RTPB 1024

__device__ __forceinline__ double shfl_down_f64(double x, int off) {
  union { double d; int i[2]; } u; u.d = x;
  u.i[0] = __shfl_down(u.i[0], off, 64);
  u.i[1] = __shfl_down(u.i[1], off, 64);
  return u.d;
}

// ---- DPP wave64 inclusive add-scan (VALU-only, no ds_bpermute) ----
// canonical gfx9 sequence: row_shr 1/2/4/8 (zero-fill), bcast15 (rows 1,3),
// bcast31 (rows 2,3). Masked-off rows add old=0.
template<int CTRL, int RM, int BM, bool BC>
__device__ __forceinline__ float dppf(float x) {
  return __int_as_float(__builtin_amdgcn_update_dpp(
      0, __float_as_int(x), CTRL, RM, BM, BC));
}
template<int CTRL, int RM, int BM, bool BC>
__device__ __forceinline__ double dppd(double x) {
  union { double d; int i[2]; } u, o; u.d = x;
  o.i[0] = __builtin_amdgcn_update_dpp(0, u.i[0], CTRL, RM, BM, BC);
  o.i[1] = __builtin_amdgcn_update_dpp(0, u.i[1], CTRL, RM, BM, BC);
  return o.d;
}
__device__ __forceinline__ void iscan2(float& a, float& b) {
  a += dppf<0x111,0xF,0xF,true >(a);  b += dppf<0x111,0xF,0xF,true >(b);
  a += dppf<0x112,0xF,0xF,true >(a);  b += dppf<0x112,0xF,0xF,true >(b);
  a += dppf<0x114,0xF,0xF,true >(a);  b += dppf<0x114,0xF,0xF,true >(b);
  a += dppf<0x118,0xF,0xF,true >(a);  b += dppf<0x118,0xF,0xF,true >(b);
  a += dppf<0x142,0xa,0xF,false>(a);  b += dppf<0x142,0xa,0xF,false>(b);
  a += dppf<0x143,0xc,0xF,false>(a);  b += dppf<0x143,0xc,0xF,false>(b);
}
__device__ __forceinline__ void iscan2d(double& a, double& b) {
  a += dppd<0x111,0xF,0xF,true >(a);  b += dppd<0x111,0xF,0xF,true >(b);
  a += dppd<0x112,0xF,0xF,true >(a);  b += dppd<0x112,0xF,0xF,true >(b);
  a += dppd<0x114,0xF,0xF,true >(a);  b += dppd<0x114,0xF,0xF,true >(b);
  a += dppd<0x118,0xF,0xF,true >(a);  b += dppd<0x118,0xF,0xF,true >(b);
  a += dppd<0x142,0xa,0xF,false>(a);  b += dppd<0x142,0xa,0xF,false>(b);
  a += dppd<0x143,0xc,0xF,false>(a);  b += dppd<0x143,0xc,0xF,false>(b);
}

// ---------------- setup: banded inverse of T = (1/256)*tridiag(1,4,1), 255x255 --------
__global__ void w2_setup(float* __restrict__ bandS) {
  __shared__ double sh_L[256];
  __shared__ double sh_winv[256];
  const int tid = threadIdx.x;
  if (tid < 255) {
    double d, dm;
    if (tid >= 20) {
      d = dm = 3.7320508075688772935;          // 2+sqrt(3), fully converged
    } else {
      d = 4.0; dm = 0.0;
      for (int i = 1; i <= tid; i++) { dm = d; d = 4.0 - 1.0 / d; }
    }
    sh_winv[tid] = 256.0 / d;
    sh_L[tid] = (tid == 0) ? 0.0 : 1.0 / dm;
  }
  __syncthreads();
  const int j = tid;
  const double H = (double)H_P;
  if (j < 255) {
    double y[BW + 1];
    y[0] = 1.0;
    #pragma unroll
    for (int m = 1; m <= BW; m++) {
      int i = j + m;
      y[m] = (i <= 254) ? (-sh_L[i] * y[m - 1]) : 0.0;
    }
    double xn = 0.0;
    #pragma unroll
    for (int m = BW; m >= 0; m--) {
      int i = j + m;
      double val = 0.0;
      if (i <= 254) {
        double num = y[m] - ((i < 254) ? H * xn : 0.0);
        val = num * sh_winv[i];
        xn = val;
      }
      bandS[(m + BW) * 256 + j] = (float)val;
    }
    #pragma unroll
    for (int m = -1; m >= -BW; m--) {
      int i = j + m;
      double val = 0.0;
      if (i >= 0) {
        val = (-H * xn) * sh_winv[i];
        xn = val;
      }
      bandS[(m + BW) * 256 + j] = (float)val;
    }
  } else {
    for (int mm = 0; mm < BD; mm++) bandS[mm * 256 + j] = 0.0f;
  }
}

// ---------------- main: TWO traces per block, interleaved A/B pipelines ---------------
// NOTE (round 3): no min-waves arg in __launch_bounds__ (VGPR squeeze -> HBM spill).
// NOTE (round 5): no same-address atomic fusion of the final reduce (+135 us).
// NOTE (round 8): wave-per-row regressed (occupancy 19%, 4x serial chunk scans).
// Scans via DPP (VALU) instead of ds_bpermute; excl stays a shfl COPY so the
// scatter's bit-exact neighbor-boundary property is preserved.
__global__ __launch_bounds__(TPB) void w2_main(
    const float* __restrict__ f, const float* __restrict__ obs,
    const float* __restrict__ t, const float* __restrict__ bandS,
    double* __restrict__ row_out) {
  __shared__ float s_qA[NQ_], s_qB[NQ_];
  __shared__ float s_rhsA[255 + 2 * BW], s_rhsB[255 + 2 * BW];
  __shared__ float s_MA[NQ_], s_MB[NQ_];
  __shared__ float4 s_coefA[256], s_coefB[256];
  __shared__ float s_wfA[4], s_wfB[4], s_wf2A[4], s_wf2B[4];
  __shared__ double s_wdA[4], s_wdB[4];
  __shared__ double s_miscA[2], s_miscB[2];

  const int tid = threadIdx.x;
  const int lane = tid & 63;
  const int wid = tid >> 6;
  const int rowA = (int)blockIdx.x * 2;
  const int rowB = rowA + 1;
  const int base = tid * EPT;
  const int emax = (tid == TPB - 1) ? EPT - 1 : EPT;

  const double dx = (double)t[1] - (double)t[0];

  float tl[EPT + 1];
  {
    const float4 a = *reinterpret_cast<const float4*>(t + base);
    const float4 b = *reinterpret_cast<const float4*>(t + base + 4);
    tl[0] = a.x; tl[1] = a.y; tl[2] = a.z; tl[3] = a.w;
    tl[4] = b.x; tl[5] = b.y; tl[6] = b.z; tl[7] = b.w;
  }
  tl[EPT] = (tid < TPB - 1) ? t[base + EPT] : 0.0f;

  // ================= Phase A: obs^2 -> cdf scans (A,B interleaved) =================
  float sAA[EPT], sAB[EPT];
  float epA = 0.0f, epB = 0.0f;
  {
    const float* orA = obs + (size_t)rowA * NT_;
    const float* orB = obs + (size_t)rowB * NT_;
    float ovA[EPT + 1], ovB[EPT + 1];
    {
      const float4 a0 = *reinterpret_cast<const float4*>(orA + base);
      const float4 a1 = *reinterpret_cast<const float4*>(orA + base + 4);
      const float4 b0 = *reinterpret_cast<const float4*>(orB + base);
      const float4 b1 = *reinterpret_cast<const float4*>(orB + base + 4);
      ovA[0] = a0.x; ovA[1] = a0.y; ovA[2] = a0.z; ovA[3] = a0.w;
      ovA[4] = a1.x; ovA[5] = a1.y; ovA[6] = a1.z; ovA[7] = a1.w;
      ovB[0] = b0.x; ovB[1] = b0.y; ovB[2] = b0.z; ovB[3] = b0.w;
      ovB[4] = b1.x; ovB[5] = b1.y; ovB[6] = b1.z; ovB[7] = b1.w;
    }
    ovA[EPT] = (tid < TPB - 1) ? orA[base + EPT] : 0.0f;
    ovB[EPT] = (tid < TPB - 1) ? orB[base + EPT] : 0.0f;
    for (int k = 0; k < emax; k++) {
      sAA[k] = ovA[k] * ovA[k] + ovA[k + 1] * ovA[k + 1];
      sAB[k] = ovB[k] * ovB[k] + ovB[k + 1] * ovB[k + 1];
      epA += sAA[k];
      epB += sAB[k];
    }
    if (emax < EPT) { sAA[EPT - 1] = 0.0f; sAB[EPT - 1] = 0.0f; }
  }
  float vA = epA, vB = epB;
  iscan2(vA, vB);                                    // DPP scan, VALU-only
  float exclA = __shfl_up(vA, 1, 64);                // bit-exact copy
  float exclB = __shfl_up(vB, 1, 64);
  if (lane == 0) { exclA = 0.0f; exclB = 0.0f; }
  if (lane == 63) { s_wfA[wid] = vA; s_wfB[wid] = vB; }
  __syncthreads();                                   // B1
  float woffA = 0.0f, totA = 0.0f, woffB = 0.0f, totB = 0.0f;
  #pragma unroll
  for (int w = 0; w < 4; w++) {
    float swA = s_wfA[w], swB = s_wfB[w];
    if (w < wid) { woffA += swA; woffB += swB; }
    totA += swA; totB += swB;
  }
  float runA = woffA + exclA, inclA = woffA + vA, invA = 1.0f / totA;
  float runB = woffB + exclB, inclB = woffB + vB, invB = 1.0f / totB;

  // scatter: p[j]=j/256 exactly; p[j] <= c  <=>  j <= 256*c (256*c exact in fp32)
  {
    float cprev = fminf(runA * invA, 1.0f);
    int j = (int)(cprev * 256.0f) + 1;
    float r = runA;
    for (int k = 0; k < emax; k++) {
      float cu_uns = (k == emax - 1) ? inclA : (r + sAA[k]);
      r = cu_uns;
      float cuc = fminf(cu_uns * invA, 1.0f);
      int jh = (int)(cuc * 256.0f);
      float tq = tl[k + 1];
      for (; j <= jh; j++) s_qA[j] = tq;
    }
    if (tid == 0) s_qA[0] = tl[0];
    if (tid == TPB - 1) {
      float tq = tl[EPT - 1];
      for (; j <= 256; j++) s_qA[j] = tq;
    }
  }
  {
    float cprev = fminf(runB * invB, 1.0f);
    int j = (int)(cprev * 256.0f) + 1;
    float r = runB;
    for (int k = 0; k < emax; k++) {
      float cu_uns = (k == emax - 1) ? inclB : (r + sAB[k]);
      r = cu_uns;
      float cuc = fminf(cu_uns * invB, 1.0f);
      int jh = (int)(cuc * 256.0f);
      float tq = tl[k + 1];
      for (; j <= jh; j++) s_qB[j] = tq;
    }
    if (tid == 0) s_qB[0] = tl[0];
    if (tid == TPB - 1) {
      float tq = tl[EPT - 1];
      for (; j <= 256; j++) s_qB[j] = tq;
    }
  }

  // ---- Phase B front half: f^2 squares + wave scans (A,B interleaved) ----
  const float* frA = f + (size_t)rowA * NT_;
  const float* frB = f + (size_t)rowB * NT_;
  float fvA[EPT + 1], fvB[EPT + 1];
  {
    const float4 a0 = *reinterpret_cast<const float4*>(frA + base);
    const float4 a1 = *reinterpret_cast<const float4*>(frA + base + 4);
    const float4 b0 = *reinterpret_cast<const float4*>(frB + base);
    const float4 b1 = *reinterpret_cast<const float4*>(frB + base + 4);
    fvA[0] = a0.x; fvA[1] = a0.y; fvA[2] = a0.z; fvA[3] = a0.w;
    fvA[4] = a1.x; fvA[5] = a1.y; fvA[6] = a1.z; fvA[7] = a1.w;
    fvB[0] = b0.x; fvB[1] = b0.y; fvB[2] = b0.z; fvB[3] = b0.w;
    fvB[4] = b1.x; fvB[5] = b1.y; fvB[6] = b1.z; fvB[7] = b1.w;
  }
  fvA[EPT] = (tid < TPB - 1) ? frA[base + EPT] : 0.0f;
  fvB[EPT] = (tid < TPB - 1) ? frB[base + EPT] : 0.0f;

  float sBA[EPT], sBB[EPT];
  float ep2A = 0.0f, ep2B = 0.0f;
  for (int k = 0; k < emax; k++) {
    sBA[k] = fvA[k] * fvA[k] + fvA[k + 1] * fvA[k + 1];
    sBB[k] = fvB[k] * fvB[k] + fvB[k + 1] * fvB[k + 1];
    ep2A += sBA[k];
    ep2B += sBB[k];
  }
  if (emax < EPT) { sBA[EPT - 1] = 0.0f; sBB[EPT - 1] = 0.0f; }
  float v2A = ep2A, v2B = ep2B;
  iscan2(v2A, v2B);                                  // DPP scan
  float excl2A = __shfl_up(v2A, 1, 64);
  float excl2B = __shfl_up(v2B, 1, 64);
  if (lane == 0) { excl2A = 0.0f; excl2B = 0.0f; }
  if (lane == 63) { s_wf2A[wid] = v2A; s_wf2B[wid] = v2B; }
  __syncthreads();                                   // B2 (s_q* + s_wf2* ready)

  float woff2A = 0.0f, tot2A = 0.0f, woff2B = 0.0f, tot2B = 0.0f;
  #pragma unroll
  for (int w = 0; w < 4; w++) {
    float swA = s_wf2A[w], swB = s_wf2B[w];
    if (w < wid) { woff2A += swA; woff2B += swB; }
    tot2A += swA; tot2B += swB;
  }
  float run2A = woff2A + excl2A, inv2A = 1.0f / tot2A;
  float run2B = woff2B + excl2B, inv2B = 1.0f / tot2B;

  if (tid < 255) {
    float sl0A = (s_qA[tid + 1] - s_qA[tid]) * 256.0f;
    float sl1A = (s_qA[tid + 2] - s_qA[tid + 1]) * 256.0f;
    s_rhsA[BW + tid] = 6.0f * (sl1A - sl0A);
    float sl0B = (s_qB[tid + 1] - s_qB[tid]) * 256.0f;
    float sl1B = (s_qB[tid + 2] - s_qB[tid + 1]) * 256.0f;
    s_rhsB[BW + tid] = 6.0f * (sl1B - sl0B);
  }
  if (tid < BW) { s_rhsA[tid] = 0.0f; s_rhsB[tid] = 0.0f; }
  if (tid >= TPB - BW) {
    s_rhsA[tid + (2 * BW - 1)] = 0.0f;
    s_rhsB[tid + (2 * BW - 1)] = 0.0f;
  }
  __syncthreads();                                   // B3

  float MregA = 0.0f, MregB = 0.0f;
  if (tid < 255) {
    #pragma unroll 11
    for (int dd = 0; dd < BD; dd++) {
      float w = bandS[dd * 256 + tid];               // one load feeds both rows
      MregA += w * s_rhsA[tid + dd];
      MregB += w * s_rhsB[tid + dd];
    }
  }
  if (tid < 255) { s_MA[tid + 1] = MregA; s_MB[tid + 1] = MregB; }
  if (tid == 0) { s_MA[0] = 0.0f; s_MA[256] = 0.0f; s_MB[0] = 0.0f; s_MB[256] = 0.0f; }
  __syncthreads();                                   // B4

  {
    const float h = H_P;
    float q0A = s_qA[tid], q1A = s_qA[tid + 1];
    float MiA = s_MA[tid], Mi1A = s_MA[tid + 1];
    float slA = (q1A - q0A) * 256.0f;
    float bA = slA - h * (2.0f * MiA + Mi1A) * (1.0f / 6.0f);
    s_coefA[tid] = make_float4(q0A, bA, 0.5f * MiA, (Mi1A - MiA) * (256.0f / 6.0f));
    float q0B = s_qB[tid], q1B = s_qB[tid + 1];
    float MiB = s_MB[tid], Mi1B = s_MB[tid + 1];
    float slB = (q1B - q0B) * 256.0f;
    float bB = slB - h * (2.0f * MiB + Mi1B) * (1.0f / 6.0f);
    s_coefB[tid] = make_float4(q0B, bB, 0.5f * MiB, (Mi1B - MiB) * (256.0f / 6.0f));
  }
  __syncthreads();                                   // B5

  // ================= Phase B back half: spline eval + weighted trapz ================
  double wsumA = 0.0, wsumB = 0.0;
  {
    float r2A = run2A, r2B = run2B;
    #pragma unroll
    for (int k = 0; k < EPT; k++) {
      if (k > 0) { r2A += sBA[k - 1]; r2B += sBB[k - 1]; }
      float FA = r2A * inv2A;
      float FB = r2B * inv2B;
      int idxA = (int)ceilf(FA * 256.0f) - 1;        // searchsorted(p,F,'left')-1
      int idxB = (int)ceilf(FB * 256.0f) - 1;
      if (idxA < 0) idxA = 0; if (idxA > 255) idxA = 255;
      if (idxB < 0) idxB = 0; if (idxB > 255) idxB = 255;
      float fracA = FA - (float)idxA * H_P;
      float fracB = FB - (float)idxB * H_P;
      float4 cfA = s_coefA[idxA];
      float4 cfB = s_coefB[idxB];
      float valA = cfA.x + fracA * (cfA.y + fracA * (cfA.z + fracA * cfA.w));
      float valB = cfB.x + fracB * (cfB.y + fracB * (cfB.z + fracB * cfB.w));
      float diffA = tl[k] - valA;
      float diffB = tl[k] - valB;
      float wvA = diffA * diffA * fvA[k];
      float wvB = diffB * diffB * fvB[k];
      if (tid == 0 && k == 0) { s_miscA[0] = (double)wvA; s_miscB[0] = (double)wvB; }
      if (tid == TPB - 1 && k == EPT - 1) { s_miscA[1] = (double)wvA; s_miscB[1] = (double)wvB; }
      wsumA += (double)wvA;
      wsumB += (double)wvB;
    }
  }
  double rA = wsumA, rB = wsumB;
  iscan2d(rA, rB);                                   // DPP f64 scan; lane63 = total
  if (lane == 63) { s_wdA[wid] = rA; s_wdB[wid] = rB; }
  __syncthreads();                                   // B6
  if (tid == 0) {
    double totwA = s_wdA[0] + s_wdA[1] + s_wdA[2] + s_wdA[3];
    double totwB = s_wdB[0] + s_wdB[1] + s_wdB[2] + s_wdB[3];
    row_out[rowA] = (totwA - 0.5 * (s_miscA[0] + s_miscA[1])) * dx;
    row_out[rowB] = (totwB - 0.5 * (s_miscB[0] + s_miscB[1])) * dx;
  }
}

__global__ __launch_bounds__(RTPB) void w2_reduce(const double* __restrict__ row_out,
                                                  int ntr, float* __restrict__ out) {
  __shared__ double s[RTPB / 64];
  int tid = threadIdx.x, lane = tid & 63, wid = tid >> 6;
  double v = 0.0;
  for (int i = tid; i < ntr; i += RTPB) v += row_out[i];
  #pragma unroll
  for (int off = 32; off >= 1; off >>= 1) v += shfl_down_f64(v, off);
  if (lane == 0) s[wid] = v;
  __syncthreads();
  if (tid == 0) {
    double tot = 0.0;
    #pragma unroll
    for (int i = 0; i < RTPB / 64; i++) tot += s[i];
    out[0] = (float)tot;
  }
}

extern "C" void kernel_launch(void* const* d_in, const int* in_sizes, int n_in,
                              void* d_out, int out_size, void* d_ws, size_t ws_size,
                              hipStream_t stream) {
  const float* f   = (const float*)d_in[0];
  const float* obs = (const float*)d_in[1];
  const float* t   = (const float*)d_in[2];
  int nt = in_sizes[2];          // 2048
  int ntr = in_sizes[0] / nt;    // 4096

  float* bandS = (float*)d_ws;
  double* rows = (double*)((char*)d_ws + BAND_BYTES);

  hipLaunchKernelGGL(w2_setup, dim3(1), dim3(256), 0, stream, bandS);
  hipLaunchKernelGGL(w2_main, dim3(ntr / 2), dim3(TPB), 0, stream,
                     f, obs, t, bandS, rows);
  hipLaunchKernelGGL(w2_reduce, dim3(1), dim3(RTPB), 0, stream,
                     rows, ntr, (float*)d_out);
}

// Round 10
// 36.294 us; speedup vs baseline: 1.3400x; 1.1677x over previous
//
#include <hip/hip_runtime.h>

#define TPB 256
#define NT_ 2048
#define NQ_ 257
#define EPT 8              // NT_/TPB
#define BW 8               // band half-width of T^-1 (tap decay 0.268^d; 0.268^9~7e-6)
#define BD (2*BW+1)        // 17
#define H_P 0.00390625f    // p spacing = 1/256, exact
#define RTPB 1024

// ---------------- compile-time band: inverse of T = tridiag(h,4h,h), h=1/256 ----------
// p is exactly linspace(0,1,257) (harness-fixed), so T is a compile-time constant.
// Same double-precision Thomas elimination the old setup kernel ran, evaluated by the
// constexpr interpreter; removes one kernel launch + gap per call.
struct Band { float v[BD * 256]; };
constexpr Band make_band() {
  Band b{};
  double L[256] = {}, winv[256] = {};
  const double H = 1.0 / 256.0;
  double w = 4.0 * H;
  winv[0] = 1.0 / w;
  L[0] = 0.0;
  for (int i = 1; i < 255; i++) {
    L[i] = H * winv[i - 1];
    w = 4.0 * H - L[i] * H;
    winv[i] = 1.0 / w;
  }
  for (int j = 0; j < 255; j++) {
    double y[BW + 1] = {};
    y[0] = 1.0;
    for (int m = 1; m <= BW; m++) {
      int i = j + m;
      y[m] = (i <= 254) ? (-L[i] * y[m - 1]) : 0.0;
    }
    double xn = 0.0;
    for (int m = BW; m >= 0; m--) {
      int i = j + m;
      double val = 0.0;
      if (i <= 254) {
        double num = y[m] - ((i < 254) ? H * xn : 0.0);
        val = num * winv[i];
        xn = val;
      }
      b.v[(m + BW) * 256 + j] = (float)val;
    }
    for (int m = -1; m >= -BW; m--) {
      int i = j + m;
      double val = 0.0;
      if (i >= 0) {
        val = (-H * xn) * winv[i];
        xn = val;
      }
      b.v[(m + BW) * 256 + j] = (float)val;
    }
  }
  return b;   // column 255 stays zero (aggregate zero-init)
}
__device__ __constant__ Band g_band = make_band();

__device__ __forceinline__ double shfl_down_f64(double x, int off) {
  union { double d; int i[2]; } u; u.d = x;
  u.i[0] = __shfl_down(u.i[0], off, 64);
  u.i[1] = __shfl_down(u.i[1], off, 64);
  return u.d;
}

// ---- DPP wave64 inclusive add-scan (VALU-only, no ds_bpermute) ----
template<int CTRL, int RM, int BM, bool BC>
__device__ __forceinline__ float dppf(float x) {
  return __int_as_float(__builtin_amdgcn_update_dpp(
      0, __float_as_int(x), CTRL, RM, BM, BC));
}
template<int CTRL, int RM, int BM, bool BC>
__device__ __forceinline__ double dppd(double x) {
  union { double d; int i[2]; } u, o; u.d = x;
  o.i[0] = __builtin_amdgcn_update_dpp(0, u.i[0], CTRL, RM, BM, BC);
  o.i[1] = __builtin_amdgcn_update_dpp(0, u.i[1], CTRL, RM, BM, BC);
  return o.d;
}
__device__ __forceinline__ void iscan2(float& a, float& b) {
  a += dppf<0x111,0xF,0xF,true >(a);  b += dppf<0x111,0xF,0xF,true >(b);
  a += dppf<0x112,0xF,0xF,true >(a);  b += dppf<0x112,0xF,0xF,true >(b);
  a += dppf<0x114,0xF,0xF,true >(a);  b += dppf<0x114,0xF,0xF,true >(b);
  a += dppf<0x118,0xF,0xF,true >(a);  b += dppf<0x118,0xF,0xF,true >(b);
  a += dppf<0x142,0xa,0xF,false>(a);  b += dppf<0x142,0xa,0xF,false>(b);
  a += dppf<0x143,0xc,0xF,false>(a);  b += dppf<0x143,0xc,0xF,false>(b);
}
__device__ __forceinline__ void iscan2d(double& a, double& b) {
  a += dppd<0x111,0xF,0xF,true >(a);  b += dppd<0x111,0xF,0xF,true >(b);
  a += dppd<0x112,0xF,0xF,true >(a);  b += dppd<0x112,0xF,0xF,true >(b);
  a += dppd<0x114,0xF,0xF,true >(a);  b += dppd<0x114,0xF,0xF,true >(b);
  a += dppd<0x118,0xF,0xF,true >(a);  b += dppd<0x118,0xF,0xF,true >(b);
  a += dppd<0x142,0xa,0xF,false>(a);  b += dppd<0x142,0xa,0xF,false>(b);
  a += dppd<0x143,0xc,0xF,false>(a);  b += dppd<0x143,0xc,0xF,false>(b);
}

// ---------------- main: TWO traces per block, interleaved A/B pipelines ---------------
// NOTE (round 3): no min-waves arg in __launch_bounds__ (VGPR squeeze -> HBM spill).
// NOTE (round 5): no same-address atomic fusion of the final reduce (+135 us).
// NOTE (round 8): wave-per-row regressed (occupancy 19%, 4x serial chunk scans).
__global__ __launch_bounds__(TPB) void w2_main(
    const float* __restrict__ f, const float* __restrict__ obs,
    const float* __restrict__ t, double* __restrict__ row_out) {
  __shared__ float s_qA[NQ_], s_qB[NQ_];
  __shared__ float s_rhsA[255 + 2 * BW], s_rhsB[255 + 2 * BW];
  __shared__ float s_MA[NQ_], s_MB[NQ_];
  __shared__ float4 s_coefA[256], s_coefB[256];
  __shared__ float s_wfA[4], s_wfB[4], s_wf2A[4], s_wf2B[4];
  __shared__ double s_wdA[4], s_wdB[4];
  __shared__ double s_miscA[2], s_miscB[2];

  const int tid = threadIdx.x;
  const int lane = tid & 63;
  const int wid = tid >> 6;
  const int rowA = (int)blockIdx.x * 2;
  const int rowB = rowA + 1;
  const int base = tid * EPT;
  const int emax = (tid == TPB - 1) ? EPT - 1 : EPT;

  const double dx = (double)t[1] - (double)t[0];

  float tl[EPT + 1];
  {
    const float4 a = *reinterpret_cast<const float4*>(t + base);
    const float4 b = *reinterpret_cast<const float4*>(t + base + 4);
    tl[0] = a.x; tl[1] = a.y; tl[2] = a.z; tl[3] = a.w;
    tl[4] = b.x; tl[5] = b.y; tl[6] = b.z; tl[7] = b.w;
  }
  tl[EPT] = (tid < TPB - 1) ? t[base + EPT] : 0.0f;

  // ================= Phase A: obs^2 -> cdf scans (A,B interleaved) =================
  float sAA[EPT], sAB[EPT];
  float epA = 0.0f, epB = 0.0f;
  {
    const float* orA = obs + (size_t)rowA * NT_;
    const float* orB = obs + (size_t)rowB * NT_;
    float ovA[EPT + 1], ovB[EPT + 1];
    {
      const float4 a0 = *reinterpret_cast<const float4*>(orA + base);
      const float4 a1 = *reinterpret_cast<const float4*>(orA + base + 4);
      const float4 b0 = *reinterpret_cast<const float4*>(orB + base);
      const float4 b1 = *reinterpret_cast<const float4*>(orB + base + 4);
      ovA[0] = a0.x; ovA[1] = a0.y; ovA[2] = a0.z; ovA[3] = a0.w;
      ovA[4] = a1.x; ovA[5] = a1.y; ovA[6] = a1.z; ovA[7] = a1.w;
      ovB[0] = b0.x; ovB[1] = b0.y; ovB[2] = b0.z; ovB[3] = b0.w;
      ovB[4] = b1.x; ovB[5] = b1.y; ovB[6] = b1.z; ovB[7] = b1.w;
    }
    ovA[EPT] = (tid < TPB - 1) ? orA[base + EPT] : 0.0f;
    ovB[EPT] = (tid < TPB - 1) ? orB[base + EPT] : 0.0f;
    for (int k = 0; k < emax; k++) {
      sAA[k] = ovA[k] * ovA[k] + ovA[k + 1] * ovA[k + 1];
      sAB[k] = ovB[k] * ovB[k] + ovB[k + 1] * ovB[k + 1];
      epA += sAA[k];
      epB += sAB[k];
    }
    if (emax < EPT) { sAA[EPT - 1] = 0.0f; sAB[EPT - 1] = 0.0f; }
  }
  float vA = epA, vB = epB;
  iscan2(vA, vB);                                    // DPP scan, VALU-only
  float exclA = __shfl_up(vA, 1, 64);                // bit-exact copy
  float exclB = __shfl_up(vB, 1, 64);
  if (lane == 0) { exclA = 0.0f; exclB = 0.0f; }
  if (lane == 63) { s_wfA[wid] = vA; s_wfB[wid] = vB; }
  __syncthreads();                                   // B1
  float woffA = 0.0f, totA = 0.0f, woffB = 0.0f, totB = 0.0f;
  #pragma unroll
  for (int w = 0; w < 4; w++) {
    float swA = s_wfA[w], swB = s_wfB[w];
    if (w < wid) { woffA += swA; woffB += swB; }
    totA += swA; totB += swB;
  }
  float runA = woffA + exclA, inclA = woffA + vA, invA = 1.0f / totA;
  float runB = woffB + exclB, inclB = woffB + vB, invB = 1.0f / totB;

  // scatter: p[j]=j/256 exactly; p[j] <= c  <=>  j <= 256*c (256*c exact in fp32)
  {
    float cprev = fminf(runA * invA, 1.0f);
    int j = (int)(cprev * 256.0f) + 1;
    float r = runA;
    for (int k = 0; k < emax; k++) {
      float cu_uns = (k == emax - 1) ? inclA : (r + sAA[k]);
      r = cu_uns;
      float cuc = fminf(cu_uns * invA, 1.0f);
      int jh = (int)(cuc * 256.0f);
      float tq = tl[k + 1];
      for (; j <= jh; j++) s_qA[j] = tq;
    }
    if (tid == 0) s_qA[0] = tl[0];
    if (tid == TPB - 1) {
      float tq = tl[EPT - 1];
      for (; j <= 256; j++) s_qA[j] = tq;
    }
  }
  {
    float cprev = fminf(runB * invB, 1.0f);
    int j = (int)(cprev * 256.0f) + 1;
    float r = runB;
    for (int k = 0; k < emax; k++) {
      float cu_uns = (k == emax - 1) ? inclB : (r + sAB[k]);
      r = cu_uns;
      float cuc = fminf(cu_uns * invB, 1.0f);
      int jh = (int)(cuc * 256.0f);
      float tq = tl[k + 1];
      for (; j <= jh; j++) s_qB[j] = tq;
    }
    if (tid == 0) s_qB[0] = tl[0];
    if (tid == TPB - 1) {
      float tq = tl[EPT - 1];
      for (; j <= 256; j++) s_qB[j] = tq;
    }
  }

  // ---- Phase B front half: f^2 squares + wave scans (A,B interleaved) ----
  const float* frA = f + (size_t)rowA * NT_;
  const float* frB = f + (size_t)rowB * NT_;
  float fvA[EPT + 1], fvB[EPT + 1];
  {
    const float4 a0 = *reinterpret_cast<const float4*>(frA + base);
    const float4 a1 = *reinterpret_cast<const float4*>(frA + base + 4);
    const float4 b0 = *reinterpret_cast<const float4*>(frB + base);
    const float4 b1 = *reinterpret_cast<const float4*>(frB + base + 4);
    fvA[0] = a0.x; fvA[1] = a0.y; fvA[2] = a0.z; fvA[3] = a0.w;
    fvA[4] = a1.x; fvA[5] = a1.y; fvA[6] = a1.z; fvA[7] = a1.w;
    fvB[0] = b0.x; fvB[1] = b0.y; fvB[2] = b0.z; fvB[3] = b0.w;
    fvB[4] = b1.x; fvB[5] = b1.y; fvB[6] = b1.z; fvB[7] = b1.w;
  }
  fvA[EPT] = (tid < TPB - 1) ? frA[base + EPT] : 0.0f;
  fvB[EPT] = (tid < TPB - 1) ? frB[base + EPT] : 0.0f;

  float sBA[EPT], sBB[EPT];
  float ep2A = 0.0f, ep2B = 0.0f;
  for (int k = 0; k < emax; k++) {
    sBA[k] = fvA[k] * fvA[k] + fvA[k + 1] * fvA[k + 1];
    sBB[k] = fvB[k] * fvB[k] + fvB[k + 1] * fvB[k + 1];
    ep2A += sBA[k];
    ep2B += sBB[k];
  }
  if (emax < EPT) { sBA[EPT - 1] = 0.0f; sBB[EPT - 1] = 0.0f; }
  float v2A = ep2A, v2B = ep2B;
  iscan2(v2A, v2B);                                  // DPP scan
  float excl2A = __shfl_up(v2A, 1, 64);
  float excl2B = __shfl_up(v2B, 1, 64);
  if (lane == 0) { excl2A = 0.0f; excl2B = 0.0f; }
  if (lane == 63) { s_wf2A[wid] = v2A; s_wf2B[wid] = v2B; }
  __syncthreads();                                   // B2 (s_q* + s_wf2* ready)

  float woff2A = 0.0f, tot2A = 0.0f, woff2B = 0.0f, tot2B = 0.0f;
  #pragma unroll
  for (int w = 0; w < 4; w++) {
    float swA = s_wf2A[w], swB = s_wf2B[w];
    if (w < wid) { woff2A += swA; woff2B += swB; }
    tot2A += swA; tot2B += swB;
  }
  float run2A = woff2A + excl2A, inv2A = 1.0f / tot2A;
  float run2B = woff2B + excl2B, inv2B = 1.0f / tot2B;

  if (tid < 255) {
    float sl0A = (s_qA[tid + 1] - s_qA[tid]) * 256.0f;
    float sl1A = (s_qA[tid + 2] - s_qA[tid + 1]) * 256.0f;
    s_rhsA[BW + tid] = 6.0f * (sl1A - sl0A);
    float sl0B = (s_qB[tid + 1] - s_qB[tid]) * 256.0f;
    float sl1B = (s_qB[tid + 2] - s_qB[tid + 1]) * 256.0f;
    s_rhsB[BW + tid] = 6.0f * (sl1B - sl0B);
  }
  if (tid < BW) { s_rhsA[tid] = 0.0f; s_rhsB[tid] = 0.0f; }
  if (tid >= TPB - BW) {
    s_rhsA[tid + (2 * BW - 1)] = 0.0f;   // [BW+255, 255+2BW)
    s_rhsB[tid + (2 * BW - 1)] = 0.0f;
  }
  __syncthreads();                                   // B3

  float MregA = 0.0f, MregB = 0.0f;
  if (tid < 255) {
    #pragma unroll
    for (int dd = 0; dd < BD; dd++) {
      float w = g_band.v[dd * 256 + tid];            // compile-time band, L1/L2-hot
      MregA += w * s_rhsA[tid + dd];
      MregB += w * s_rhsB[tid + dd];
    }
  }
  if (tid < 255) { s_MA[tid + 1] = MregA; s_MB[tid + 1] = MregB; }
  if (tid == 0) { s_MA[0] = 0.0f; s_MA[256] = 0.0f; s_MB[0] = 0.0f; s_MB[256] = 0.0f; }
  __syncthreads();                                   // B4

  {
    const float h = H_P;
    float q0A = s_qA[tid], q1A = s_qA[tid + 1];
    float MiA = s_MA[tid], Mi1A = s_MA[tid + 1];
    float slA = (q1A - q0A) * 256.0f;
    float bA = slA - h * (2.0f * MiA + Mi1A) * (1.0f / 6.0f);
    s_coefA[tid] = make_float4(q0A, bA, 0.5f * MiA, (Mi1A - MiA) * (256.0f / 6.0f));
    float q0B = s_qB[tid], q1B = s_qB[tid + 1];
    float MiB = s_MB[tid], Mi1B = s_MB[tid + 1];
    float slB = (q1B - q0B) * 256.0f;
    float bB = slB - h * (2.0f * MiB + Mi1B) * (1.0f / 6.0f);
    s_coefB[tid] = make_float4(q0B, bB, 0.5f * MiB, (Mi1B - MiB) * (256.0f / 6.0f));
  }
  __syncthreads();                                   // B5

  // ================= Phase B back half: spline eval + weighted trapz ================
  float csumA = 0.0f, csumB = 0.0f;                  // fp32 inner 8-term sums
  {
    float r2A = run2A, r2B = run2B;
    #pragma unroll
    for (int k = 0; k < EPT; k++) {
      if (k > 0) { r2A += sBA[k - 1]; r2B += sBB[k - 1]; }
      float FA = r2A * inv2A;
      float FB = r2B * inv2B;
      int idxA = (int)ceilf(FA * 256.0f) - 1;        // searchsorted(p,F,'left')-1
      int idxB = (int)ceilf(FB * 256.0f) - 1;
      if (idxA < 0) idxA = 0; if (idxA > 255) idxA = 255;
      if (idxB < 0) idxB = 0; if (idxB > 255) idxB = 255;
      float fracA = FA - (float)idxA * H_P;
      float fracB = FB - (float)idxB * H_P;
      float4 cfA = s_coefA[idxA];
      float4 cfB = s_coefB[idxB];
      float valA = cfA.x + fracA * (cfA.y + fracA * (cfA.z + fracA * cfA.w));
      float valB = cfB.x + fracB * (cfB.y + fracB * (cfB.z + fracB * cfB.w));
      float diffA = tl[k] - valA;
      float diffB = tl[k] - valB;
      float wvA = diffA * diffA * fvA[k];
      float wvB = diffB * diffB * fvB[k];
      if (tid == 0 && k == 0) { s_miscA[0] = (double)wvA; s_miscB[0] = (double)wvB; }
      if (tid == TPB - 1 && k == EPT - 1) { s_miscA[1] = (double)wvA; s_miscB[1] = (double)wvB; }
      csumA += wvA;
      csumB += wvB;
    }
  }
  double rA = (double)csumA, rB = (double)csumB;
  iscan2d(rA, rB);                                   // DPP f64 scan; lane63 = total
  if (lane == 63) { s_wdA[wid] = rA; s_wdB[wid] = rB; }
  __syncthreads();                                   // B6
  if (tid == 0) {
    double totwA = s_wdA[0] + s_wdA[1] + s_wdA[2] + s_wdA[3];
    double totwB = s_wdB[0] + s_wdB[1] + s_wdB[2] + s_wdB[3];
    row_out[rowA] = (totwA - 0.5 * (s_miscA[0] + s_miscA[1])) * dx;
    row_out[rowB] = (totwB - 0.5 * (s_miscB[0] + s_miscB[1])) * dx;
  }
}

__global__ __launch_bounds__(RTPB) void w2_reduce(const double* __restrict__ row_out,
                                                  int ntr, float* __restrict__ out) {
  __shared__ double s[RTPB / 64];
  int tid = threadIdx.x, lane = tid & 63, wid = tid >> 6;
  double v = 0.0;
  for (int i = tid; i < ntr; i += RTPB) v += row_out[i];
  #pragma unroll
  for (int off = 32; off >= 1; off >>= 1) v += shfl_down_f64(v, off);
  if (lane == 0) s[wid] = v;
  __syncthreads();
  if (tid == 0) {
    double tot = 0.0;
    #pragma unroll
    for (int i = 0; i < RTPB / 64; i++) tot += s[i];
    out[0] = (float)tot;
  }
}

extern "C" void kernel_launch(void* const* d_in, const int* in_sizes, int n_in,
                              void* d_out, int out_size, void* d_ws, size_t ws_size,
                              hipStream_t stream) {
  const float* f   = (const float*)d_in[0];
  const float* obs = (const float*)d_in[1];
  const float* t   = (const float*)d_in[2];
  int nt = in_sizes[2];          // 2048
  int ntr = in_sizes[0] / nt;    // 4096

  double* rows = (double*)d_ws;

  hipLaunchKernelGGL(w2_main, dim3(ntr / 2), dim3(TPB), 0, stream,
                     f, obs, t, rows);
  hipLaunchKernelGGL(w2_reduce, dim3(1), dim3(RTPB), 0, stream,
                     rows, ntr, (float*)d_out);
}

// Round 11
// 35.801 us; speedup vs baseline: 1.3585x; 1.0138x over previous
//
#include <hip/hip_runtime.h>

#define TPB 256
#define NT_ 2048
#define NQ_ 257
#define EPT 8              // NT_/TPB
#define BWQ 5              // tap half-width in rhs-space (decay 0.268^d)
#define BWS (BWQ + 2)      // band half-width kept for S when composing
#define BD2 (2*BWQ + 3)    // 13 taps over q
#define PQ BWQ             // leading pad of s_q
#define QLEN (PQ + NQ_ + BWQ + 2)   // 5 + 257 + 7 = 269
#define H_P 0.00390625f    // p spacing = 1/256, exact
#define RTPB 1024

// ------ compile-time composed band: W = 1536 * Tinv * D^2  (M[i+1] = W_i . q) ------
// T = tridiag(h,4h,h), h=1/256 (p is exactly linspace(0,1,257));
// rhs[j] = 6*256*(q[j] - 2 q[j+1] + q[j+2]);  M_inner = Tinv * rhs  ==>
// M[i+1] = sum_n W[i][n] q[n],  W[i][n] = 1536*(S[i][n] - 2 S[i][n-1] + S[i][n-2]),
// n in [i-BWQ, i+BWQ+2].  S row i obtained from column i by symmetry.
struct Band { float v[BD2 * 256]; };
constexpr Band make_band() {
  Band b{};
  double L[256] = {}, winv[256] = {};
  const double H = 1.0 / 256.0;
  winv[0] = 1.0 / (4.0 * H);
  L[0] = 0.0;
  for (int i = 1; i < 255; i++) {
    L[i] = H * winv[i - 1];
    winv[i] = 1.0 / (4.0 * H - L[i] * H);
  }
  for (int i = 0; i < 255; i++) {
    double col[2 * BWS + 1] = {};        // col[d+BWS] = S[i][i+d]
    double y[BWS + 1] = {};
    y[0] = 1.0;
    for (int m = 1; m <= BWS; m++) {
      int idx = i + m;
      y[m] = (idx <= 254) ? (-L[idx] * y[m - 1]) : 0.0;
    }
    double xn = 0.0;
    for (int m = BWS; m >= 0; m--) {
      int idx = i + m;
      double val = 0.0;
      if (idx <= 254) {
        double num = y[m] - ((idx < 254) ? H * xn : 0.0);
        val = num * winv[idx];
        xn = val;
      }
      col[m + BWS] = val;
    }
    for (int m = -1; m >= -BWS; m--) {
      int idx = i + m;
      double val = 0.0;
      if (idx >= 0) {
        val = (-H * xn) * winv[idx];
        xn = val;
      }
      col[m + BWS] = val;
    }
    for (int mm = 0; mm < BD2; mm++) {
      int n = i - BWQ + mm;              // q index
      double w = 0.0;
      if (n >= 0 && n <= 256) {
        double s0 = 0.0, s1 = 0.0, s2 = 0.0;
        int d0 = n - i, d1 = n - 1 - i, d2 = n - 2 - i;
        if (n     >= 0 && n     <= 254 && d0 >= -BWS && d0 <= BWS) s0 = col[d0 + BWS];
        if (n - 1 >= 0 && n - 1 <= 254 && d1 >= -BWS && d1 <= BWS) s1 = col[d1 + BWS];
        if (n - 2 >= 0 && n - 2 <= 254 && d2 >= -BWS && d2 <= BWS) s2 = col[d2 + BWS];
        w = 1536.0 * (s0 - 2.0 * s1 + s2);
      }
      b.v[mm * 256 + i] = (float)w;
    }
  }
  return b;   // row 255 stays zero (M[256]=0)
}
__device__ __constant__ Band g_band = make_band();

__device__ __forceinline__ double shfl_down_f64(double x, int off) {
  union { double d; int i[2]; } u; u.d = x;
  u.i[0] = __shfl_down(u.i[0], off, 64);
  u.i[1] = __shfl_down(u.i[1], off, 64);
  return u.d;
}

// ---- DPP wave64 inclusive add-scan (VALU-only, no ds_bpermute) ----
template<int CTRL, int RM, int BM, bool BC>
__device__ __forceinline__ float dppf(float x) {
  return __int_as_float(__builtin_amdgcn_update_dpp(
      0, __float_as_int(x), CTRL, RM, BM, BC));
}
template<int CTRL, int RM, int BM, bool BC>
__device__ __forceinline__ double dppd(double x) {
  union { double d; int i[2]; } u, o; u.d = x;
  o.i[0] = __builtin_amdgcn_update_dpp(0, u.i[0], CTRL, RM, BM, BC);
  o.i[1] = __builtin_amdgcn_update_dpp(0, u.i[1], CTRL, RM, BM, BC);
  return o.d;
}
__device__ __forceinline__ void iscan2(float& a, float& b) {
  a += dppf<0x111,0xF,0xF,true >(a);  b += dppf<0x111,0xF,0xF,true >(b);
  a += dppf<0x112,0xF,0xF,true >(a);  b += dppf<0x112,0xF,0xF,true >(b);
  a += dppf<0x114,0xF,0xF,true >(a);  b += dppf<0x114,0xF,0xF,true >(b);
  a += dppf<0x118,0xF,0xF,true >(a);  b += dppf<0x118,0xF,0xF,true >(b);
  a += dppf<0x142,0xa,0xF,false>(a);  b += dppf<0x142,0xa,0xF,false>(b);
  a += dppf<0x143,0xc,0xF,false>(a);  b += dppf<0x143,0xc,0xF,false>(b);
}
__device__ __forceinline__ void iscan2d(double& a, double& b) {
  a += dppd<0x111,0xF,0xF,true >(a);  b += dppd<0x111,0xF,0xF,true >(b);
  a += dppd<0x112,0xF,0xF,true >(a);  b += dppd<0x112,0xF,0xF,true >(b);
  a += dppd<0x114,0xF,0xF,true >(a);  b += dppd<0x114,0xF,0xF,true >(b);
  a += dppd<0x118,0xF,0xF,true >(a);  b += dppd<0x118,0xF,0xF,true >(b);
  a += dppd<0x142,0xa,0xF,false>(a);  b += dppd<0x142,0xa,0xF,false>(b);
  a += dppd<0x143,0xc,0xF,false>(a);  b += dppd<0x143,0xc,0xF,false>(b);
}

// ---------------- main: TWO traces per block, interleaved A/B pipelines ---------------
// NOTE (round 3): no min-waves arg in __launch_bounds__ (VGPR squeeze -> HBM spill).
// NOTE (round 5): no same-address atomic fusion of the final reduce (+135 us).
// NOTE (round 8): wave-per-row regressed (occupancy 19%, 4x serial chunk scans).
// NOTE (round 11): rhs phase folded into compile-time band (M = W.q); M neighbor
// via shfl_up + 4-value LDS handoff; eval & scatter in 256x-scaled space (bitwise
// equivalent: pow2 scaling commutes with fp rounding).
__global__ __launch_bounds__(TPB) void w2_main(
    const float* __restrict__ f, const float* __restrict__ obs,
    const float* __restrict__ t, double* __restrict__ row_out) {
  __shared__ float s_qA[QLEN], s_qB[QLEN];
  __shared__ float4 s_coefA[256], s_coefB[256];
  __shared__ float s_wfA[4], s_wfB[4], s_wf2A[4], s_wf2B[4];
  __shared__ double s_wdA[4], s_wdB[4];
  __shared__ double s_miscA[2], s_miscB[2];

  const int tid = threadIdx.x;
  const int lane = tid & 63;
  const int wid = tid >> 6;
  const int rowA = (int)blockIdx.x * 2;
  const int rowB = rowA + 1;
  const int base = tid * EPT;
  const int emax = (tid == TPB - 1) ? EPT - 1 : EPT;

  const double dx = (double)t[1] - (double)t[0];

  // zero the q pads (read by the 13-tap MV; weights there are 0 but must be finite)
  if (tid < PQ) { s_qA[tid] = 0.0f; s_qB[tid] = 0.0f; }
  if (tid >= TPB - (BWQ + 2)) {
    int o = PQ + NQ_ + tid - (TPB - (BWQ + 2));
    s_qA[o] = 0.0f; s_qB[o] = 0.0f;
  }

  float tl[EPT + 1];
  {
    const float4 a = *reinterpret_cast<const float4*>(t + base);
    const float4 b = *reinterpret_cast<const float4*>(t + base + 4);
    tl[0] = a.x; tl[1] = a.y; tl[2] = a.z; tl[3] = a.w;
    tl[4] = b.x; tl[5] = b.y; tl[6] = b.z; tl[7] = b.w;
  }
  tl[EPT] = (tid < TPB - 1) ? t[base + EPT] : 0.0f;

  // ================= Phase A: obs^2 -> cdf scans (A,B interleaved) =================
  float sAA[EPT], sAB[EPT];
  float epA = 0.0f, epB = 0.0f;
  {
    const float* orA = obs + (size_t)rowA * NT_;
    const float* orB = obs + (size_t)rowB * NT_;
    float ovA[EPT + 1], ovB[EPT + 1];
    {
      const float4 a0 = *reinterpret_cast<const float4*>(orA + base);
      const float4 a1 = *reinterpret_cast<const float4*>(orA + base + 4);
      const float4 b0 = *reinterpret_cast<const float4*>(orB + base);
      const float4 b1 = *reinterpret_cast<const float4*>(orB + base + 4);
      ovA[0] = a0.x; ovA[1] = a0.y; ovA[2] = a0.z; ovA[3] = a0.w;
      ovA[4] = a1.x; ovA[5] = a1.y; ovA[6] = a1.z; ovA[7] = a1.w;
      ovB[0] = b0.x; ovB[1] = b0.y; ovB[2] = b0.z; ovB[3] = b0.w;
      ovB[4] = b1.x; ovB[5] = b1.y; ovB[6] = b1.z; ovB[7] = b1.w;
    }
    ovA[EPT] = (tid < TPB - 1) ? orA[base + EPT] : 0.0f;
    ovB[EPT] = (tid < TPB - 1) ? orB[base + EPT] : 0.0f;
    for (int k = 0; k < emax; k++) {
      sAA[k] = ovA[k] * ovA[k] + ovA[k + 1] * ovA[k + 1];
      sAB[k] = ovB[k] * ovB[k] + ovB[k + 1] * ovB[k + 1];
      epA += sAA[k];
      epB += sAB[k];
    }
    if (emax < EPT) { sAA[EPT - 1] = 0.0f; sAB[EPT - 1] = 0.0f; }
  }
  float vA = epA, vB = epB;
  iscan2(vA, vB);                                    // DPP scan, VALU-only
  float exclA = __shfl_up(vA, 1, 64);                // bit-exact copy
  float exclB = __shfl_up(vB, 1, 64);
  if (lane == 0) { exclA = 0.0f; exclB = 0.0f; }
  if (lane == 63) { s_wfA[wid] = vA; s_wfB[wid] = vB; }
  __syncthreads();                                   // B1
  float woffA = 0.0f, totA = 0.0f, woffB = 0.0f, totB = 0.0f;
  #pragma unroll
  for (int w = 0; w < 4; w++) {
    float swA = s_wfA[w], swB = s_wfB[w];
    if (w < wid) { woffA += swA; woffB += swB; }
    totA += swA; totB += swB;
  }
  float runA = woffA + exclA, inclA = woffA + vA;
  float runB = woffB + exclB, inclB = woffB + vB;
  // 256/tot == (1/tot)*256 bitwise (pow2 scale commutes with rounding)
  float invA256 = 256.0f / totA;
  float invB256 = 256.0f / totB;

  // scatter: p[j]=j/256 exactly; p[j] <= c  <=>  j <= 256*c (scaled space)
  {
    float cprevS = fminf(runA * invA256, 256.0f);
    int j = (int)cprevS + 1;
    float r = runA;
    for (int k = 0; k < emax; k++) {
      float cu_uns = (k == emax - 1) ? inclA : (r + sAA[k]);
      r = cu_uns;
      float cuS = fminf(cu_uns * invA256, 256.0f);
      int jh = (int)cuS;
      float tq = tl[k + 1];
      for (; j <= jh; j++) s_qA[PQ + j] = tq;
    }
    if (tid == 0) s_qA[PQ + 0] = tl[0];
    if (tid == TPB - 1) {
      float tq = tl[EPT - 1];
      for (; j <= 256; j++) s_qA[PQ + j] = tq;
    }
  }
  {
    float cprevS = fminf(runB * invB256, 256.0f);
    int j = (int)cprevS + 1;
    float r = runB;
    for (int k = 0; k < emax; k++) {
      float cu_uns = (k == emax - 1) ? inclB : (r + sAB[k]);
      r = cu_uns;
      float cuS = fminf(cu_uns * invB256, 256.0f);
      int jh = (int)cuS;
      float tq = tl[k + 1];
      for (; j <= jh; j++) s_qB[PQ + j] = tq;
    }
    if (tid == 0) s_qB[PQ + 0] = tl[0];
    if (tid == TPB - 1) {
      float tq = tl[EPT - 1];
      for (; j <= 256; j++) s_qB[PQ + j] = tq;
    }
  }

  // ---- Phase B front half: f^2 squares + wave scans (A,B interleaved) ----
  const float* frA = f + (size_t)rowA * NT_;
  const float* frB = f + (size_t)rowB * NT_;
  float fvA[EPT + 1], fvB[EPT + 1];
  {
    const float4 a0 = *reinterpret_cast<const float4*>(frA + base);
    const float4 a1 = *reinterpret_cast<const float4*>(frA + base + 4);
    const float4 b0 = *reinterpret_cast<const float4*>(frB + base);
    const float4 b1 = *reinterpret_cast<const float4*>(frB + base + 4);
    fvA[0] = a0.x; fvA[1] = a0.y; fvA[2] = a0.z; fvA[3] = a0.w;
    fvA[4] = a1.x; fvA[5] = a1.y; fvA[6] = a1.z; fvA[7] = a1.w;
    fvB[0] = b0.x; fvB[1] = b0.y; fvB[2] = b0.z; fvB[3] = b0.w;
    fvB[4] = b1.x; fvB[5] = b1.y; fvB[6] = b1.z; fvB[7] = b1.w;
  }
  fvA[EPT] = (tid < TPB - 1) ? frA[base + EPT] : 0.0f;
  fvB[EPT] = (tid < TPB - 1) ? frB[base + EPT] : 0.0f;

  float sBA[EPT], sBB[EPT];
  float ep2A = 0.0f, ep2B = 0.0f;
  for (int k = 0; k < emax; k++) {
    sBA[k] = fvA[k] * fvA[k] + fvA[k + 1] * fvA[k + 1];
    sBB[k] = fvB[k] * fvB[k] + fvB[k + 1] * fvB[k + 1];
    ep2A += sBA[k];
    ep2B += sBB[k];
  }
  if (emax < EPT) { sBA[EPT - 1] = 0.0f; sBB[EPT - 1] = 0.0f; }
  float v2A = ep2A, v2B = ep2B;
  iscan2(v2A, v2B);                                  // DPP scan
  float excl2A = __shfl_up(v2A, 1, 64);
  float excl2B = __shfl_up(v2B, 1, 64);
  if (lane == 0) { excl2A = 0.0f; excl2B = 0.0f; }
  if (lane == 63) { s_wf2A[wid] = v2A; s_wf2B[wid] = v2B; }
  __syncthreads();                                   // B2 (s_q* + s_wf2* ready)

  float woff2A = 0.0f, tot2A = 0.0f, woff2B = 0.0f, tot2B = 0.0f;
  #pragma unroll
  for (int w = 0; w < 4; w++) {
    float swA = s_wf2A[w], swB = s_wf2B[w];
    if (w < wid) { woff2A += swA; woff2B += swB; }
    tot2A += swA; tot2B += swB;
  }
  float run2A = woff2A + excl2A, inv2A256 = 256.0f / tot2A;
  float run2B = woff2B + excl2B, inv2B256 = 256.0f / tot2B;

  // ---- banded MV directly over q: Mreg = M[tid+1] ----
  float MregA = 0.0f, MregB = 0.0f;
  if (tid < 255) {
    #pragma unroll
    for (int mm = 0; mm < BD2; mm++) {
      float w = g_band.v[mm * 256 + tid];            // compile-time W = 1536*S*D^2
      MregA += w * s_qA[tid + mm];                   // q index tid-BWQ+mm, +PQ pad
      MregB += w * s_qB[tid + mm];
    }
  }
  float MprevA = __shfl_up(MregA, 1, 64);            // M[tid] for lane>0
  float MprevB = __shfl_up(MregB, 1, 64);
  if (lane == 63) { s_wfA[wid] = MregA; s_wfB[wid] = MregB; }  // reuse (post-B2)
  __syncthreads();                                   // B3 (wave-boundary M handoff)
  if (lane == 0) {
    MprevA = (wid == 0) ? 0.0f : s_wfA[wid - 1];
    MprevB = (wid == 0) ? 0.0f : s_wfB[wid - 1];
  }

  {
    const float h = H_P;
    // coef in u-space (u = 256*frac): scale b,c,d by 2^-8, 2^-16, 2^-24 (exact)
    float q0A = s_qA[PQ + tid], q1A = s_qA[PQ + tid + 1];
    float slA = (q1A - q0A) * 256.0f;
    float bA = slA - h * (2.0f * MprevA + MregA) * (1.0f / 6.0f);
    float cA = 0.5f * MprevA;
    float dA = (MregA - MprevA) * (256.0f / 6.0f);
    s_coefA[tid] = make_float4(q0A, bA * (1.0f / 256.0f),
                               cA * (1.0f / 65536.0f), dA * (1.0f / 16777216.0f));
    float q0B = s_qB[PQ + tid], q1B = s_qB[PQ + tid + 1];
    float slB = (q1B - q0B) * 256.0f;
    float bB = slB - h * (2.0f * MprevB + MregB) * (1.0f / 6.0f);
    float cB = 0.5f * MprevB;
    float dB = (MregB - MprevB) * (256.0f / 6.0f);
    s_coefB[tid] = make_float4(q0B, bB * (1.0f / 256.0f),
                               cB * (1.0f / 65536.0f), dB * (1.0f / 16777216.0f));
  }
  __syncthreads();                                   // B4 (coef ready)

  // ================= Phase B back half: spline eval + weighted trapz ================
  float csumA = 0.0f, csumB = 0.0f;                  // fp32 inner 8-term sums
  {
    float r2A = run2A, r2B = run2B;
    #pragma unroll
    for (int k = 0; k < EPT; k++) {
      if (k > 0) { r2A += sBA[k - 1]; r2B += sBB[k - 1]; }
      float GA = r2A * inv2A256;                     // == F*256 bitwise
      float GB = r2B * inv2B256;
      float fiA = ceilf(GA) - 1.0f;                  // searchsorted(p,F,'left')-1
      float fiB = ceilf(GB) - 1.0f;
      fiA = fminf(fmaxf(fiA, 0.0f), 255.0f);
      fiB = fminf(fmaxf(fiB, 0.0f), 255.0f);
      int idxA = (int)fiA;
      int idxB = (int)fiB;
      float uA = GA - fiA;                           // == 256*frac bitwise
      float uB = GB - fiB;
      float4 cfA = s_coefA[idxA];
      float4 cfB = s_coefB[idxB];
      float valA = cfA.x + uA * (cfA.y + uA * (cfA.z + uA * cfA.w));
      float valB = cfB.x + uB * (cfB.y + uB * (cfB.z + uB * cfB.w));
      float diffA = tl[k] - valA;
      float diffB = tl[k] - valB;
      float wvA = diffA * diffA * fvA[k];
      float wvB = diffB * diffB * fvB[k];
      if (tid == 0 && k == 0) { s_miscA[0] = (double)wvA; s_miscB[0] = (double)wvB; }
      if (tid == TPB - 1 && k == EPT - 1) { s_miscA[1] = (double)wvA; s_miscB[1] = (double)wvB; }
      csumA += wvA;
      csumB += wvB;
    }
  }
  double rA = (double)csumA, rB = (double)csumB;
  iscan2d(rA, rB);                                   // DPP f64 scan; lane63 = total
  if (lane == 63) { s_wdA[wid] = rA; s_wdB[wid] = rB; }
  __syncthreads();                                   // B5
  if (tid == 0) {
    double totwA = s_wdA[0] + s_wdA[1] + s_wdA[2] + s_wdA[3];
    double totwB = s_wdB[0] + s_wdB[1] + s_wdB[2] + s_wdB[3];
    row_out[rowA] = (totwA - 0.5 * (s_miscA[0] + s_miscA[1])) * dx;
    row_out[rowB] = (totwB - 0.5 * (s_miscB[0] + s_miscB[1])) * dx;
  }
}

__global__ __launch_bounds__(RTPB) void w2_reduce(const double* __restrict__ row_out,
                                                  int ntr, float* __restrict__ out) {
  __shared__ double s[RTPB / 64];
  int tid = threadIdx.x, lane = tid & 63, wid = tid >> 6;
  double v = 0.0;
  for (int i = tid; i < ntr; i += RTPB) v += row_out[i];
  #pragma unroll
  for (int off = 32; off >= 1; off >>= 1) v += shfl_down_f64(v, off);
  if (lane == 0) s[wid] = v;
  __syncthreads();
  if (tid == 0) {
    double tot = 0.0;
    #pragma unroll
    for (int i = 0; i < RTPB / 64; i++) tot += s[i];
    out[0] = (float)tot;
  }
}

extern "C" void kernel_launch(void* const* d_in, const int* in_sizes, int n_in,
                              void* d_out, int out_size, void* d_ws, size_t ws_size,
                              hipStream_t stream) {
  const float* f   = (const float*)d_in[0];
  const float* obs = (const float*)d_in[1];
  const float* t   = (const float*)d_in[2];
  int nt = in_sizes[2];          // 2048
  int ntr = in_sizes[0] / nt;    // 4096

  double* rows = (double*)d_ws;

  hipLaunchKernelGGL(w2_main, dim3(ntr / 2), dim3(TPB), 0, stream,
                     f, obs, t, rows);
  hipLaunchKernelGGL(w2_reduce, dim3(1), dim3(RTPB), 0, stream,
                     rows, ntr, (float*)d_out);
}